// Round 19
// baseline (289.382 us; speedup 1.0000x reference)
//
#include <hip/hip_runtime.h>
#include <hip/hip_fp16.h>
#include <math.h>

#define D 64
#define NPB 64           // nodes per bucket
#define NPB_SHIFT 6
#define LCAP 2560        // LDS capacity per bucket (mean ~1024)
#define NPART 512        // edge partitions (2 blocks/CU)
#define NV 2             // nodes owned per 8-lane group in agg_kernel

typedef _Float16 half4v __attribute__((ext_vector_type(4)));
typedef float f32x4 __attribute__((ext_vector_type(4)));
typedef float f32x2v __attribute__((ext_vector_type(2)));

// ---------------- scan chain: scan1 + scan2; scan3 folded into consumers ----------------

__global__ void scan1_kernel(const int* __restrict__ in, int* __restrict__ out,
                             int* __restrict__ bsum, int n) {
    __shared__ int s[1024];
    int t = threadIdx.x;
    int i = blockIdx.x * 1024 + t;
    int v = (i < n) ? in[i] : 0;
    s[t] = v;
    __syncthreads();
    for (int off = 1; off < 1024; off <<= 1) {
        int add = (t >= off) ? s[t - off] : 0;
        __syncthreads();
        s[t] += add;
        __syncthreads();
    }
    if (i < n) out[i] = s[t] - v;
    if (t == 1023) bsum[blockIdx.x] = s[1023];
}

__global__ void scan2_kernel(int* __restrict__ bsum, int nb) {
    __shared__ int s[1024];
    int t = threadIdx.x;
    int v = (t < nb) ? bsum[t] : 0;
    s[t] = v;
    __syncthreads();
    for (int off = 1; off < 1024; off <<= 1) {
        int add = (t >= off) ? s[t - off] : 0;
        __syncthreads();
        s[t] += add;
        __syncthreads();
    }
    if (t < nb) bsum[t] = s[t] - v;
}

// ---------------- hist (blocks < NPART) + f2f8 (blocks >= NPART), one dispatch ----------------

__global__ __launch_bounds__(256) void hist_f2f8_kernel(
    const int* __restrict__ dst, int* __restrict__ harr,
    int e, int nb, int chunk,
    const float* __restrict__ fin, unsigned char* __restrict__ f8out, int n4)
{
    extern __shared__ int sh[];
    if ((int)blockIdx.x < NPART) {
        const int p = blockIdx.x;
        for (int i = threadIdx.x; i < nb; i += 256) sh[i] = 0;
        __syncthreads();
        const int s = p * chunk, ee = min(e, s + chunk);
        for (int i = s + threadIdx.x; i < ee; i += 256)
            atomicAdd(&sh[dst[i] >> NPB_SHIFT], 1);
        __syncthreads();
        for (int b = threadIdx.x; b < nb; b += 256) harr[b * NPART + p] = sh[b];
    } else {
        int i = (blockIdx.x - NPART) * 256 + threadIdx.x;
        if (i < n4) {
            float4 v = *(const float4*)(fin + (size_t)i * 4);
            int pk0 = __builtin_amdgcn_cvt_pk_fp8_f32(v.x, v.y, 0, false);
            int pk1 = __builtin_amdgcn_cvt_pk_fp8_f32(v.z, v.w, 0, false);
            ((unsigned int*)f8out)[i] = (unsigned int)(pk0 & 0xFFFF) | ((unsigned int)(pk1 & 0xFFFF) << 16);
        }
    }
}

// soff_full(i) = soff[i] + bsum[i>>10]  (scan3 folded)
__global__ __launch_bounds__(256) void part_scatter_kernel(
    const int* __restrict__ src, const int* __restrict__ dst,
    const int* __restrict__ soff, const int* __restrict__ bsum,
    int* __restrict__ packed, int e, int nb, int chunk)
{
    extern __shared__ int cur[];
    const int p = blockIdx.x;
    for (int b = threadIdx.x; b < nb; b += 256) {
        int idx = b * NPART + p;
        cur[b] = soff[idx] + bsum[idx >> 10];
    }
    __syncthreads();
    const int s = p * chunk, ee = min(e, s + chunk);
    for (int i = s + threadIdx.x; i < ee; i += 256) {
        int d = dst[i];
        int pos = atomicAdd(&cur[d >> NPB_SHIFT], 1);
        packed[pos] = src[i] | ((d & (NPB - 1)) << 24);
    }
}

// per-bucket: dst-sort packed in LDS, emit csr (src only) + rs
__global__ __launch_bounds__(256) void bucket_build_kernel(
    const int* __restrict__ soff, const int* __restrict__ bsum,
    const int* __restrict__ packed,
    int* __restrict__ csr, int* __restrict__ rs,
    int n, int e_total, int nb)
{
    __shared__ int lcsr[LCAP];
    __shared__ int dcount[NPB];
    __shared__ int dexcl[NPB];
    __shared__ int cur2[NPB];
    const int b    = blockIdx.x;
    const int i0x  = b * NPART;
    const int base = soff[i0x] + bsum[i0x >> 10];
    int end;
    if (b + 1 < nb) {
        const int i1x = (b + 1) * NPART;
        end = soff[i1x] + bsum[i1x >> 10];
    } else {
        end = e_total;
    }
    const int cnt  = end - base;
    const int nb0  = b << NPB_SHIFT;
    const int nnode = min(NPB, n - nb0);
    const int tid  = threadIdx.x;

    if (tid < NPB) { dcount[tid] = 0; cur2[tid] = 0; }
    __syncthreads();

    for (int i = tid; i < cnt; i += 256)
        atomicAdd(&dcount[(packed[base + i] >> 24) & (NPB - 1)], 1);
    __syncthreads();
    if (tid == 0) {
        int run = 0;
        for (int t = 0; t < nnode; ++t) { dexcl[t] = run; run += dcount[t]; }
    }
    __syncthreads();
    if (tid < nnode) rs[nb0 + tid] = base + dexcl[tid];

    if (cnt <= LCAP) {
        for (int i = tid; i < cnt; i += 256) {
            int pk = packed[base + i];
            int ln = (pk >> 24) & (NPB - 1);
            int pos = dexcl[ln] + atomicAdd(&cur2[ln], 1);
            lcsr[pos] = pk & 0xFFFFFF;
        }
        __syncthreads();
        for (int i = tid; i < cnt; i += 256) csr[base + i] = lcsr[i];
    } else {
        for (int i = tid; i < cnt; i += 256) {
            int pk = packed[base + i];
            int ln = (pk >> 24) & (NPB - 1);
            int pos = dexcl[ln] + atomicAdd(&cur2[ln], 1);
            csr[base + pos] = pk & 0xFFFFFF;
        }
    }
}

// ---------------- fp8 -> f32 unpack helper ----------------

__device__ __forceinline__ void cvt8(int2 w, float* x) {
    f32x2v a0 = __builtin_amdgcn_cvt_pk_f32_fp8(w.x, false);
    f32x2v a1 = __builtin_amdgcn_cvt_pk_f32_fp8(w.x, true);
    f32x2v a2 = __builtin_amdgcn_cvt_pk_f32_fp8(w.y, false);
    f32x2v a3 = __builtin_amdgcn_cvt_pk_f32_fp8(w.y, true);
    x[0] = a0[0]; x[1] = a0[1]; x[2] = a1[0]; x[3] = a1[1];
    x[4] = a2[0]; x[5] = a2[1]; x[6] = a3[0]; x[7] = a3[1];
}

// ---------------- aggregation: node-owned fp8 gather, prefetch-4 ----------------

__global__ __launch_bounds__(256) void agg_kernel(
    const unsigned char* __restrict__ in8, const int* __restrict__ csr,
    const int* __restrict__ rs, __half* __restrict__ anorm,
    int n, int e_total)
{
    const int ll = threadIdx.x & 7;
    const int g  = (blockIdx.x * 256 + threadIdx.x) >> 3;
    const int v0 = g * NV;
    if (v0 >= n) return;

    #pragma unroll
    for (int t = 0; t < NV; ++t) {
        const int v = v0 + t;
        if (v >= n) break;
        const int i0 = rs[v];
        const int i1 = (v + 1 < n) ? rs[v + 1] : e_total;
        const int m  = i1 - i0;

        float acc[8];
        #pragma unroll
        for (int j = 0; j < 8; ++j) acc[j] = 0.0f;

        int2 f0, f1, f2, f3;
        if (m > 0) f0 = *(const int2*)(in8 + ((size_t)csr[i0] << 6) + (ll << 3));
        if (m > 1) f1 = *(const int2*)(in8 + ((size_t)csr[i0 + 1] << 6) + (ll << 3));
        if (m > 2) f2 = *(const int2*)(in8 + ((size_t)csr[i0 + 2] << 6) + (ll << 3));
        if (m > 3) f3 = *(const int2*)(in8 + ((size_t)csr[i0 + 3] << 6) + (ll << 3));
        for (int i = 0; i < m; ++i) {
            int2 fn;
            if (i + 4 < m) fn = *(const int2*)(in8 + ((size_t)csr[i0 + i + 4] << 6) + (ll << 3));
            float x[8]; cvt8(f0, x);
            #pragma unroll
            for (int j = 0; j < 8; ++j) acc[j] += x[j];
            f0 = f1; f1 = f2; f2 = f3; f3 = fn;
        }

        int2 sf = *(const int2*)(in8 + ((size_t)v << 6) + (ll << 3));
        float sx[8]; cvt8(sf, sx);
        const float inv = 1.0f / (float)(m + 1);
        union { __half h[8]; float4 f; } u;
        #pragma unroll
        for (int j = 0; j < 8; ++j) u.h[j] = __float2half((acc[j] + sx[j]) * inv);
        *(float4*)(anorm + (size_t)v * D + ll * 8) = u.f;
    }
}

// ---------------- post: [16 x 64] @ [64 x 64] via v_mfma_f32_16x16x16f16 ----------------
// AMAX=1: also wave-reduce max|o| and atomicMax into global (for fp4 scale)

template<int RELU, int AMAX>
__global__ __launch_bounds__(256) void post_mfma_kernel(
    const __half* __restrict__ anorm, unsigned char* __restrict__ out8,
    const float* __restrict__ W, const float* __restrict__ bias, int n,
    unsigned int* __restrict__ amax)
{
    const int lane = threadIdx.x & 63;
    const int w    = threadIdx.x >> 6;
    const int tile = blockIdx.x * 4 + w;
    const int v0   = tile * 16;
    if (v0 >= n) return;

    const int col = lane & 15;
    const int kb  = (lane >> 4) * 4;

    half4v bf[4][4];
    #pragma unroll
    for (int kt = 0; kt < 4; ++kt)
        #pragma unroll
        for (int t = 0; t < 4; ++t)
            #pragma unroll
            for (int j = 0; j < 4; ++j)
                bf[kt][t][j] = (_Float16)W[(kt * 16 + kb + j) * D + t * 16 + col];

    int vr = v0 + col; if (vr >= n) vr = n - 1;
    const __half* ap = anorm + (size_t)vr * D + kb;
    half4v af[4];
    #pragma unroll
    for (int kt = 0; kt < 4; ++kt)
        af[kt] = *(const half4v*)(ap + kt * 16);

    f32x4 c[4];
    #pragma unroll
    for (int t = 0; t < 4; ++t) {
        float bv = bias[t * 16 + col];
        c[t] = (f32x4){bv, bv, bv, bv};
    }
    #pragma unroll
    for (int kt = 0; kt < 4; ++kt)
        #pragma unroll
        for (int t = 0; t < 4; ++t)
            c[t] = __builtin_amdgcn_mfma_f32_16x16x16f16(af[kt], bf[kt][t], c[t], 0, 0, 0);

    float lm = 0.0f;
    #pragma unroll
    for (int t = 0; t < 4; ++t)
        #pragma unroll
        for (int p = 0; p < 4; ++p) {
            int r = v0 + (lane >> 4) * 4 + p;
            if (r < n) {
                float o = c[t][p];
                if (RELU) o = fmaxf(o, 0.0f);
                if (AMAX) lm = fmaxf(lm, fabsf(o));
                int pk = __builtin_amdgcn_cvt_pk_fp8_f32(o, o, 0, false);
                out8[(size_t)r * D + t * 16 + col] = (unsigned char)(pk & 0xFF);
            }
        }
    if (AMAX) {
        #pragma unroll
        for (int s = 1; s < 64; s <<= 1) lm = fmaxf(lm, __shfl_xor(lm, s));
        if (lane == 0) atomicMax(amax, __float_as_uint(lm));
    }
}

// ---------------- fp8 -> fp4(e2m1) quantize with global scale 6/amax ----------------
// group of 8 elems -> 4 bytes; byte i = elem i | elem (i+4) << 4

__global__ __launch_bounds__(256) void quant4_kernel(
    const unsigned char* __restrict__ emb8, unsigned int* __restrict__ emb4,
    const unsigned int* __restrict__ amax, int ngroups)
{
    int gid = blockIdx.x * 256 + threadIdx.x;
    if (gid >= ngroups) return;
    float am = __uint_as_float(*amax);
    float scale = 6.0f / fmaxf(am, 1e-20f);
    int2 w = *(const int2*)(emb8 + (size_t)gid * 8);
    float x[8]; cvt8(w, x);
    unsigned out = 0;
    #pragma unroll
    for (int j = 0; j < 4; ++j) {
        #pragma unroll
        for (int h = 0; h < 2; ++h) {
            float v = x[j + h * 4] * scale;
            float a = fabsf(v);
            unsigned t = (unsigned)(a > 0.25f) + (a > 0.75f) + (a > 1.25f) + (a > 1.75f)
                       + (a > 2.5f) + (a > 3.5f) + (a > 5.0f);
            unsigned nib = t | (v < 0.0f ? 8u : 0u);
            out |= nib << (j * 8 + h * 4);
        }
    }
    emb4[gid] = out;
}

// ---------------- fp4 -> fp8x8 unpack (perm nibble-LUT) ----------------
// pool bytes: e2m1 magnitude t=0..7 -> e4m3 {0,0x30,0x38,0x3C,0x40,0x44,0x48,0x4C}

__device__ __forceinline__ long fp4_to_fp8x8(unsigned w) {
    const unsigned POOL_LO = 0x3C383000u;
    const unsigned POOL_HI = 0x4C484440u;
    unsigned sel_lo = w & 0x07070707u;
    unsigned sel_hi = (w >> 4) & 0x07070707u;
    unsigned sg_lo  = (w & 0x08080808u) << 4;
    unsigned sg_hi  = ((w >> 4) & 0x08080808u) << 4;
    unsigned lo = __builtin_amdgcn_perm(POOL_HI, POOL_LO, sel_lo) | sg_lo;
    unsigned hi = __builtin_amdgcn_perm(POOL_HI, POOL_LO, sel_hi) | sg_hi;
    return (long)(((unsigned long)hi << 32) | (unsigned long)lo);
}

// ---------------- Scoring: pos+neg one dispatch; fp4 rows (32 B), fp8 MFMA ----------------

__device__ __forceinline__ float softplus_fast(float x) {
    return fmaxf(x, 0.0f) + __logf(1.0f + __expf(-fabsf(x)));
}

__global__ __launch_bounds__(256) void score_both_kernel(
    const unsigned int* __restrict__ emb4,
    const int* __restrict__ pos_src, const int* __restrict__ pos_dst,
    const int* __restrict__ neg_src, const int* __restrict__ neg_dst,
    int ep, int eneg, int pblocks, const unsigned int* __restrict__ amax,
    double* __restrict__ accum)
{
    const int* a_idx; const int* b_idx;
    int npairs, bid, nblk;
    float sign;
    if ((int)blockIdx.x < pblocks) {
        a_idx = pos_src; b_idx = pos_dst; npairs = ep; sign = -1.0f;
        bid = blockIdx.x; nblk = pblocks;
    } else {
        a_idx = neg_src; b_idx = neg_dst; npairs = eneg; sign = 1.0f;
        bid = blockIdx.x - pblocks; nblk = gridDim.x - pblocks;
    }

    float am = __uint_as_float(*amax);
    const float invS2 = (am * am) / 36.0f;

    const int lane = threadIdx.x & 63;
    const int gw   = (bid * 256 + (int)threadIdx.x) >> 6;
    const int nw   = (nblk * 256) >> 6;
    const int ntiles = (npairs + 15) >> 4;
    const int ftiles = npairs >> 4;

    const int pr = lane & 15;
    const int ks = lane >> 4;
    const bool has = (ks == (pr >> 2));
    const int reg  = pr & 3;

    float local = 0.0f;

    int t = gw;
    for (; t + 3 * nw < ftiles; t += 4 * nw) {
        int ti[4] = {t, t + nw, t + 2 * nw, t + 3 * nw};
        unsigned wa0[4], wa1[4], wb0[4], wb1[4];
        #pragma unroll
        for (int u = 0; u < 4; ++u) {
            int p0 = ti[u] * 16 + pr;
            size_t ba = (size_t)a_idx[p0] * 8;
            size_t bb = (size_t)b_idx[p0] * 8;
            wa0[u] = emb4[ba + ks];
            wa1[u] = emb4[ba + ks + 4];
            wb0[u] = emb4[bb + ks];
            wb1[u] = emb4[bb + ks + 4];
        }
        #pragma unroll
        for (int u = 0; u < 4; ++u) {
            f32x4 cv = {0.f, 0.f, 0.f, 0.f};
            cv = __builtin_amdgcn_mfma_f32_16x16x32_fp8_fp8(fp4_to_fp8x8(wa0[u]), fp4_to_fp8x8(wb0[u]), cv, 0, 0, 0);
            cv = __builtin_amdgcn_mfma_f32_16x16x32_fp8_fp8(fp4_to_fp8x8(wa1[u]), fp4_to_fp8x8(wb1[u]), cv, 0, 0, 0);
            if (has) local += softplus_fast(sign * cv[reg] * invS2);
        }
    }
    for (; t < ntiles; t += nw) {
        int p0 = t * 16 + pr;
        int c0 = min(p0, npairs - 1);
        size_t ba = (size_t)a_idx[c0] * 8;
        size_t bb = (size_t)b_idx[c0] * 8;
        unsigned a0 = emb4[ba + ks], a1 = emb4[ba + ks + 4];
        unsigned b0 = emb4[bb + ks], b1 = emb4[bb + ks + 4];
        f32x4 cv = {0.f, 0.f, 0.f, 0.f};
        cv = __builtin_amdgcn_mfma_f32_16x16x32_fp8_fp8(fp4_to_fp8x8(a0), fp4_to_fp8x8(b0), cv, 0, 0, 0);
        cv = __builtin_amdgcn_mfma_f32_16x16x32_fp8_fp8(fp4_to_fp8x8(a1), fp4_to_fp8x8(b1), cv, 0, 0, 0);
        if (has && p0 < npairs) local += softplus_fast(sign * cv[reg] * invS2);
    }

    __shared__ float red[256];
    red[threadIdx.x] = local;
    __syncthreads();
    for (int s = blockDim.x / 2; s > 0; s >>= 1) {
        if ((int)threadIdx.x < s) red[threadIdx.x] += red[threadIdx.x + s];
        __syncthreads();
    }
    if (threadIdx.x == 0) atomicAdd(accum, (double)red[0]);
}

__global__ void finalize_kernel(const double* __restrict__ acc, float* __restrict__ out, int ep) {
    if (threadIdx.x == 0 && blockIdx.x == 0)
        out[0] = (float)(acc[0] / (double)ep);
}

// ---------------- launch ----------------

extern "C" void kernel_launch(void* const* d_in, const int* in_sizes, int n_in,
                              void* d_out, int out_size, void* d_ws, size_t ws_size,
                              hipStream_t stream) {
    const float* features = (const float*)d_in[0];
    const float* W1 = (const float*)d_in[1];
    const float* b1 = (const float*)d_in[2];
    const float* W2 = (const float*)d_in[3];
    const float* b2 = (const float*)d_in[4];
    const int* src     = (const int*)d_in[5];
    const int* dst     = (const int*)d_in[6];
    const int* pos_src = (const int*)d_in[7];
    const int* pos_dst = (const int*)d_in[8];
    const int* neg_src = (const int*)d_in[9];
    const int* neg_dst = (const int*)d_in[10];

    const int N    = in_sizes[0] / D;
    const int E    = in_sizes[5];
    const int EP   = in_sizes[7];
    const int ENEG = in_sizes[9];
    const int NB   = (N + NPB - 1) >> NPB_SHIFT;   // 1563 for N=100000

    char* ws = (char*)d_ws;
    size_t off = 0;
    auto alloc = [&](size_t bytes) -> void* {
        void* p = ws + off;
        off += (bytes + 255) & ~(size_t)255;
        return p;
    };
    int*    rs     = (int*)alloc((size_t)(N + 64) * 4);
    int*    harr   = (int*)alloc((size_t)NB * NPART * 4);
    int*    soff   = (int*)alloc((size_t)NB * NPART * 4);
    int*    bsum   = (int*)alloc(1024 * 4);
    int*    packed = (int*)alloc((size_t)E * 4);
    int*    csr    = (int*)alloc((size_t)E * 4);
    __half* anorm  = (__half*)alloc((size_t)N * D * 2);
    unsigned char* feat8 = (unsigned char*)alloc((size_t)N * D);
    unsigned char* h8    = (unsigned char*)alloc((size_t)N * D);
    unsigned char* emb8  = (unsigned char*)alloc((size_t)N * D);
    unsigned int*  emb4  = (unsigned int*)alloc((size_t)N * D / 2);
    unsigned int*  amax  = (unsigned int*)alloc(4);
    double* acc    = (double*)alloc(8);

    hipMemsetAsync(acc, 0, 8, stream);
    hipMemsetAsync(amax, 0, 4, stream);

    const int chunk = (E + NPART - 1) / NPART;     // 3125
    const size_t ldsNB = (size_t)NB * 4;
    const int n4 = (N * D) / 4;

    hist_f2f8_kernel<<<NPART + (n4 + 255) / 256, 256, ldsNB, stream>>>(
        dst, harr, E, NB, chunk, features, feat8, n4);
    const int scn = NB * NPART;                    // 800,256
    const int nbs = (scn + 1023) / 1024;           // 782 <= 1024
    scan1_kernel<<<nbs, 1024, 0, stream>>>(harr, soff, bsum, scn);
    scan2_kernel<<<1, 1024, 0, stream>>>(bsum, nbs);
    part_scatter_kernel<<<NPART, 256, ldsNB, stream>>>(src, dst, soff, bsum, packed, E, NB, chunk);
    bucket_build_kernel<<<NB, 256, 0, stream>>>(soff, bsum, packed, csr, rs, N, E, NB);

    const int ngroups = (N + NV - 1) / NV;        // 50,000
    const int ab = (ngroups * 8 + 255) / 256;     // 1563 blocks
    const int ntiles16 = (N + 15) / 16;           // 6250
    const int pb2 = (ntiles16 + 3) / 4;           // 1563 blocks

    // layer 1
    agg_kernel<<<ab, 256, 0, stream>>>(feat8, csr, rs, anorm, N, E);
    post_mfma_kernel<1, 0><<<pb2, 256, 0, stream>>>(anorm, h8, W1, b1, N, nullptr);

    // layer 2 (+ global absmax for fp4 scale)
    agg_kernel<<<ab, 256, 0, stream>>>(h8, csr, rs, anorm, N, E);
    post_mfma_kernel<0, 1><<<pb2, 256, 0, stream>>>(anorm, emb8, W2, b2, N, amax);

    // fp8 -> fp4 table (3.2 MB, fits per-XCD L2)
    const int ng8 = N * D / 8;                    // 800,000 groups
    quant4_kernel<<<(ng8 + 255) / 256, 256, 0, stream>>>(emb8, emb4, amax, ng8);

    int pbp = ((EP + 15) / 16 + 3) / 4;  if (pbp > 2048) pbp = 2048; if (pbp < 1) pbp = 1;
    int pbn = ((ENEG + 15) / 16 + 3) / 4; if (pbn > 2048) pbn = 2048;
    score_both_kernel<<<pbp + pbn, 256, 0, stream>>>(
        emb4, pos_src, pos_dst, neg_src, neg_dst, EP, ENEG, pbp, amax, acc);

    finalize_kernel<<<1, 64, 0, stream>>>(acc, (float*)d_out, EP);
}

// Round 20
// 244.692 us; speedup vs baseline: 1.1826x; 1.1826x over previous
//
#include <hip/hip_runtime.h>
#include <hip/hip_fp16.h>
#include <math.h>

#define D 64
#define NPB 64           // nodes per bucket
#define NPB_SHIFT 6
#define LCAP 2560        // LDS capacity per bucket (mean ~1024)
#define NPART 512        // edge partitions (2 blocks/CU)
#define NV 2             // nodes owned per 8-lane group in agg_kernel
#define AMAX_SLOTS 64    // line-spread partial-max slots (stride 16 uints = 64 B)

typedef _Float16 half4v __attribute__((ext_vector_type(4)));
typedef float f32x4 __attribute__((ext_vector_type(4)));
typedef float f32x2v __attribute__((ext_vector_type(2)));

// ---------------- scan chain: scan1 + scan2; scan3 folded into consumers ----------------

__global__ void scan1_kernel(const int* __restrict__ in, int* __restrict__ out,
                             int* __restrict__ bsum, int n) {
    __shared__ int s[1024];
    int t = threadIdx.x;
    int i = blockIdx.x * 1024 + t;
    int v = (i < n) ? in[i] : 0;
    s[t] = v;
    __syncthreads();
    for (int off = 1; off < 1024; off <<= 1) {
        int add = (t >= off) ? s[t - off] : 0;
        __syncthreads();
        s[t] += add;
        __syncthreads();
    }
    if (i < n) out[i] = s[t] - v;
    if (t == 1023) bsum[blockIdx.x] = s[1023];
}

__global__ void scan2_kernel(int* __restrict__ bsum, int nb) {
    __shared__ int s[1024];
    int t = threadIdx.x;
    int v = (t < nb) ? bsum[t] : 0;
    s[t] = v;
    __syncthreads();
    for (int off = 1; off < 1024; off <<= 1) {
        int add = (t >= off) ? s[t - off] : 0;
        __syncthreads();
        s[t] += add;
        __syncthreads();
    }
    if (t < nb) bsum[t] = s[t] - v;
}

// ---------------- hist (blocks < NPART) + f2f8 (blocks >= NPART), one dispatch ----------------

__global__ __launch_bounds__(256) void hist_f2f8_kernel(
    const int* __restrict__ dst, int* __restrict__ harr,
    int e, int nb, int chunk,
    const float* __restrict__ fin, unsigned char* __restrict__ f8out, int n4)
{
    extern __shared__ int sh[];
    if ((int)blockIdx.x < NPART) {
        const int p = blockIdx.x;
        for (int i = threadIdx.x; i < nb; i += 256) sh[i] = 0;
        __syncthreads();
        const int s = p * chunk, ee = min(e, s + chunk);
        for (int i = s + threadIdx.x; i < ee; i += 256)
            atomicAdd(&sh[dst[i] >> NPB_SHIFT], 1);
        __syncthreads();
        for (int b = threadIdx.x; b < nb; b += 256) harr[b * NPART + p] = sh[b];
    } else {
        int i = (blockIdx.x - NPART) * 256 + threadIdx.x;
        if (i < n4) {
            float4 v = *(const float4*)(fin + (size_t)i * 4);
            int pk0 = __builtin_amdgcn_cvt_pk_fp8_f32(v.x, v.y, 0, false);
            int pk1 = __builtin_amdgcn_cvt_pk_fp8_f32(v.z, v.w, 0, false);
            ((unsigned int*)f8out)[i] = (unsigned int)(pk0 & 0xFFFF) | ((unsigned int)(pk1 & 0xFFFF) << 16);
        }
    }
}

// soff_full(i) = soff[i] + bsum[i>>10]  (scan3 folded)
__global__ __launch_bounds__(256) void part_scatter_kernel(
    const int* __restrict__ src, const int* __restrict__ dst,
    const int* __restrict__ soff, const int* __restrict__ bsum,
    int* __restrict__ packed, int e, int nb, int chunk)
{
    extern __shared__ int cur[];
    const int p = blockIdx.x;
    for (int b = threadIdx.x; b < nb; b += 256) {
        int idx = b * NPART + p;
        cur[b] = soff[idx] + bsum[idx >> 10];
    }
    __syncthreads();
    const int s = p * chunk, ee = min(e, s + chunk);
    for (int i = s + threadIdx.x; i < ee; i += 256) {
        int d = dst[i];
        int pos = atomicAdd(&cur[d >> NPB_SHIFT], 1);
        packed[pos] = src[i] | ((d & (NPB - 1)) << 24);
    }
}

// per-bucket: dst-sort packed in LDS, emit csr (src only) + rs
__global__ __launch_bounds__(256) void bucket_build_kernel(
    const int* __restrict__ soff, const int* __restrict__ bsum,
    const int* __restrict__ packed,
    int* __restrict__ csr, int* __restrict__ rs,
    int n, int e_total, int nb)
{
    __shared__ int lcsr[LCAP];
    __shared__ int dcount[NPB];
    __shared__ int dexcl[NPB];
    __shared__ int cur2[NPB];
    const int b    = blockIdx.x;
    const int i0x  = b * NPART;
    const int base = soff[i0x] + bsum[i0x >> 10];
    int end;
    if (b + 1 < nb) {
        const int i1x = (b + 1) * NPART;
        end = soff[i1x] + bsum[i1x >> 10];
    } else {
        end = e_total;
    }
    const int cnt  = end - base;
    const int nb0  = b << NPB_SHIFT;
    const int nnode = min(NPB, n - nb0);
    const int tid  = threadIdx.x;

    if (tid < NPB) { dcount[tid] = 0; cur2[tid] = 0; }
    __syncthreads();

    for (int i = tid; i < cnt; i += 256)
        atomicAdd(&dcount[(packed[base + i] >> 24) & (NPB - 1)], 1);
    __syncthreads();
    if (tid == 0) {
        int run = 0;
        for (int t = 0; t < nnode; ++t) { dexcl[t] = run; run += dcount[t]; }
    }
    __syncthreads();
    if (tid < nnode) rs[nb0 + tid] = base + dexcl[tid];

    if (cnt <= LCAP) {
        for (int i = tid; i < cnt; i += 256) {
            int pk = packed[base + i];
            int ln = (pk >> 24) & (NPB - 1);
            int pos = dexcl[ln] + atomicAdd(&cur2[ln], 1);
            lcsr[pos] = pk & 0xFFFFFF;
        }
        __syncthreads();
        for (int i = tid; i < cnt; i += 256) csr[base + i] = lcsr[i];
    } else {
        for (int i = tid; i < cnt; i += 256) {
            int pk = packed[base + i];
            int ln = (pk >> 24) & (NPB - 1);
            int pos = dexcl[ln] + atomicAdd(&cur2[ln], 1);
            csr[base + pos] = pk & 0xFFFFFF;
        }
    }
}

// ---------------- fp8 -> f32 unpack helper ----------------

__device__ __forceinline__ void cvt8(int2 w, float* x) {
    f32x2v a0 = __builtin_amdgcn_cvt_pk_f32_fp8(w.x, false);
    f32x2v a1 = __builtin_amdgcn_cvt_pk_f32_fp8(w.x, true);
    f32x2v a2 = __builtin_amdgcn_cvt_pk_f32_fp8(w.y, false);
    f32x2v a3 = __builtin_amdgcn_cvt_pk_f32_fp8(w.y, true);
    x[0] = a0[0]; x[1] = a0[1]; x[2] = a1[0]; x[3] = a1[1];
    x[4] = a2[0]; x[5] = a2[1]; x[6] = a3[0]; x[7] = a3[1];
}

// ---------------- aggregation: node-owned fp8 gather, prefetch-4 ----------------

__global__ __launch_bounds__(256) void agg_kernel(
    const unsigned char* __restrict__ in8, const int* __restrict__ csr,
    const int* __restrict__ rs, __half* __restrict__ anorm,
    int n, int e_total)
{
    const int ll = threadIdx.x & 7;
    const int g  = (blockIdx.x * 256 + threadIdx.x) >> 3;
    const int v0 = g * NV;
    if (v0 >= n) return;

    #pragma unroll
    for (int t = 0; t < NV; ++t) {
        const int v = v0 + t;
        if (v >= n) break;
        const int i0 = rs[v];
        const int i1 = (v + 1 < n) ? rs[v + 1] : e_total;
        const int m  = i1 - i0;

        float acc[8];
        #pragma unroll
        for (int j = 0; j < 8; ++j) acc[j] = 0.0f;

        int2 f0, f1, f2, f3;
        if (m > 0) f0 = *(const int2*)(in8 + ((size_t)csr[i0] << 6) + (ll << 3));
        if (m > 1) f1 = *(const int2*)(in8 + ((size_t)csr[i0 + 1] << 6) + (ll << 3));
        if (m > 2) f2 = *(const int2*)(in8 + ((size_t)csr[i0 + 2] << 6) + (ll << 3));
        if (m > 3) f3 = *(const int2*)(in8 + ((size_t)csr[i0 + 3] << 6) + (ll << 3));
        for (int i = 0; i < m; ++i) {
            int2 fn;
            if (i + 4 < m) fn = *(const int2*)(in8 + ((size_t)csr[i0 + i + 4] << 6) + (ll << 3));
            float x[8]; cvt8(f0, x);
            #pragma unroll
            for (int j = 0; j < 8; ++j) acc[j] += x[j];
            f0 = f1; f1 = f2; f2 = f3; f3 = fn;
        }

        int2 sf = *(const int2*)(in8 + ((size_t)v << 6) + (ll << 3));
        float sx[8]; cvt8(sf, sx);
        const float inv = 1.0f / (float)(m + 1);
        union { __half h[8]; float4 f; } u;
        #pragma unroll
        for (int j = 0; j < 8; ++j) u.h[j] = __float2half((acc[j] + sx[j]) * inv);
        *(float4*)(anorm + (size_t)v * D + ll * 8) = u.f;
    }
}

// ---------------- post: [16 x 64] @ [64 x 64] via v_mfma_f32_16x16x16f16 ----------------
// AMAX=1: block-reduced max|o| -> ONE atomicMax per block into 64 line-spread slots

template<int RELU, int AMAX>
__global__ __launch_bounds__(256) void post_mfma_kernel(
    const __half* __restrict__ anorm, unsigned char* __restrict__ out8,
    const float* __restrict__ W, const float* __restrict__ bias, int n,
    unsigned int* __restrict__ amax)
{
    const int lane = threadIdx.x & 63;
    const int w    = threadIdx.x >> 6;
    const int tile = blockIdx.x * 4 + w;
    const int v0   = tile * 16;
    float lm = 0.0f;

    if (v0 < n) {
        const int col = lane & 15;
        const int kb  = (lane >> 4) * 4;

        half4v bf[4][4];
        #pragma unroll
        for (int kt = 0; kt < 4; ++kt)
            #pragma unroll
            for (int t = 0; t < 4; ++t)
                #pragma unroll
                for (int j = 0; j < 4; ++j)
                    bf[kt][t][j] = (_Float16)W[(kt * 16 + kb + j) * D + t * 16 + col];

        int vr = v0 + col; if (vr >= n) vr = n - 1;
        const __half* ap = anorm + (size_t)vr * D + kb;
        half4v af[4];
        #pragma unroll
        for (int kt = 0; kt < 4; ++kt)
            af[kt] = *(const half4v*)(ap + kt * 16);

        f32x4 c[4];
        #pragma unroll
        for (int t = 0; t < 4; ++t) {
            float bv = bias[t * 16 + col];
            c[t] = (f32x4){bv, bv, bv, bv};
        }
        #pragma unroll
        for (int kt = 0; kt < 4; ++kt)
            #pragma unroll
            for (int t = 0; t < 4; ++t)
                c[t] = __builtin_amdgcn_mfma_f32_16x16x16f16(af[kt], bf[kt][t], c[t], 0, 0, 0);

        #pragma unroll
        for (int t = 0; t < 4; ++t)
            #pragma unroll
            for (int p = 0; p < 4; ++p) {
                int r = v0 + (lane >> 4) * 4 + p;
                if (r < n) {
                    float o = c[t][p];
                    if (RELU) o = fmaxf(o, 0.0f);
                    if (AMAX) lm = fmaxf(lm, fabsf(o));
                    int pk = __builtin_amdgcn_cvt_pk_fp8_f32(o, o, 0, false);
                    out8[(size_t)r * D + t * 16 + col] = (unsigned char)(pk & 0xFF);
                }
            }
    }

    if (AMAX) {
        __shared__ float wmax[4];
        #pragma unroll
        for (int s = 1; s < 64; s <<= 1) lm = fmaxf(lm, __shfl_xor(lm, s));
        if (lane == 0) wmax[w] = lm;
        __syncthreads();
        if (threadIdx.x == 0) {
            float m = fmaxf(fmaxf(wmax[0], wmax[1]), fmaxf(wmax[2], wmax[3]));
            atomicMax(&amax[(blockIdx.x & (AMAX_SLOTS - 1)) * 16], __float_as_uint(m));
        }
    }
}

// ---------------- fp8 -> fp4(e2m1) quantize, scale 6/amax (slots reduced per block) ----------------
// group of 8 elems -> 4 bytes; byte i = elem i | elem (i+4) << 4

__global__ __launch_bounds__(256) void quant4_kernel(
    const unsigned char* __restrict__ emb8, unsigned int* __restrict__ emb4,
    const unsigned int* __restrict__ amax, int ngroups)
{
    __shared__ float sAm;
    if (threadIdx.x == 0) {
        float m = 0.0f;
        for (int i = 0; i < AMAX_SLOTS; ++i)
            m = fmaxf(m, __uint_as_float(amax[i * 16]));
        sAm = m;
    }
    __syncthreads();
    int gid = blockIdx.x * 256 + threadIdx.x;
    if (gid >= ngroups) return;
    float scale = 6.0f / fmaxf(sAm, 1e-20f);
    int2 w = *(const int2*)(emb8 + (size_t)gid * 8);
    float x[8]; cvt8(w, x);
    unsigned out = 0;
    #pragma unroll
    for (int j = 0; j < 4; ++j) {
        #pragma unroll
        for (int h = 0; h < 2; ++h) {
            float v = x[j + h * 4] * scale;
            float a = fabsf(v);
            unsigned t = (unsigned)(a > 0.25f) + (a > 0.75f) + (a > 1.25f) + (a > 1.75f)
                       + (a > 2.5f) + (a > 3.5f) + (a > 5.0f);
            unsigned nib = t | (v < 0.0f ? 8u : 0u);
            out |= nib << (j * 8 + h * 4);
        }
    }
    emb4[gid] = out;
}

// ---------------- fp4 -> fp8x8 unpack (perm nibble-LUT) ----------------

__device__ __forceinline__ long fp4_to_fp8x8(unsigned w) {
    const unsigned POOL_LO = 0x3C383000u;
    const unsigned POOL_HI = 0x4C484440u;
    unsigned sel_lo = w & 0x07070707u;
    unsigned sel_hi = (w >> 4) & 0x07070707u;
    unsigned sg_lo  = (w & 0x08080808u) << 4;
    unsigned sg_hi  = ((w >> 4) & 0x08080808u) << 4;
    unsigned lo = __builtin_amdgcn_perm(POOL_HI, POOL_LO, sel_lo) | sg_lo;
    unsigned hi = __builtin_amdgcn_perm(POOL_HI, POOL_LO, sel_hi) | sg_hi;
    return (long)(((unsigned long)hi << 32) | (unsigned long)lo);
}

// ---------------- Scoring: pos+neg one dispatch; fp4 rows (32 B), fp8 MFMA ----------------

__device__ __forceinline__ float softplus_fast(float x) {
    return fmaxf(x, 0.0f) + __logf(1.0f + __expf(-fabsf(x)));
}

__global__ __launch_bounds__(256) void score_both_kernel(
    const unsigned int* __restrict__ emb4,
    const int* __restrict__ pos_src, const int* __restrict__ pos_dst,
    const int* __restrict__ neg_src, const int* __restrict__ neg_dst,
    int ep, int eneg, int pblocks, const unsigned int* __restrict__ amax,
    double* __restrict__ accum)
{
    __shared__ float sInv;
    if (threadIdx.x == 0) {
        float m = 0.0f;
        for (int i = 0; i < AMAX_SLOTS; ++i)
            m = fmaxf(m, __uint_as_float(amax[i * 16]));
        sInv = (m * m) / 36.0f;
    }
    __syncthreads();
    const float invS2 = sInv;

    const int* a_idx; const int* b_idx;
    int npairs, bid, nblk;
    float sign;
    if ((int)blockIdx.x < pblocks) {
        a_idx = pos_src; b_idx = pos_dst; npairs = ep; sign = -1.0f;
        bid = blockIdx.x; nblk = pblocks;
    } else {
        a_idx = neg_src; b_idx = neg_dst; npairs = eneg; sign = 1.0f;
        bid = blockIdx.x - pblocks; nblk = gridDim.x - pblocks;
    }

    const int lane = threadIdx.x & 63;
    const int gw   = (bid * 256 + (int)threadIdx.x) >> 6;
    const int nw   = (nblk * 256) >> 6;
    const int ntiles = (npairs + 15) >> 4;
    const int ftiles = npairs >> 4;

    const int pr = lane & 15;
    const int ks = lane >> 4;
    const bool has = (ks == (pr >> 2));
    const int reg  = pr & 3;

    float local = 0.0f;

    int t = gw;
    for (; t + 3 * nw < ftiles; t += 4 * nw) {
        int ti[4] = {t, t + nw, t + 2 * nw, t + 3 * nw};
        unsigned wa0[4], wa1[4], wb0[4], wb1[4];
        #pragma unroll
        for (int u = 0; u < 4; ++u) {
            int p0 = ti[u] * 16 + pr;
            size_t ba = (size_t)a_idx[p0] * 8;
            size_t bb = (size_t)b_idx[p0] * 8;
            wa0[u] = emb4[ba + ks];
            wa1[u] = emb4[ba + ks + 4];
            wb0[u] = emb4[bb + ks];
            wb1[u] = emb4[bb + ks + 4];
        }
        #pragma unroll
        for (int u = 0; u < 4; ++u) {
            f32x4 cv = {0.f, 0.f, 0.f, 0.f};
            cv = __builtin_amdgcn_mfma_f32_16x16x32_fp8_fp8(fp4_to_fp8x8(wa0[u]), fp4_to_fp8x8(wb0[u]), cv, 0, 0, 0);
            cv = __builtin_amdgcn_mfma_f32_16x16x32_fp8_fp8(fp4_to_fp8x8(wa1[u]), fp4_to_fp8x8(wb1[u]), cv, 0, 0, 0);
            if (has) local += softplus_fast(sign * cv[reg] * invS2);
        }
    }
    for (; t < ntiles; t += nw) {
        int p0 = t * 16 + pr;
        int c0 = min(p0, npairs - 1);
        size_t ba = (size_t)a_idx[c0] * 8;
        size_t bb = (size_t)b_idx[c0] * 8;
        unsigned a0 = emb4[ba + ks], a1 = emb4[ba + ks + 4];
        unsigned b0 = emb4[bb + ks], b1 = emb4[bb + ks + 4];
        f32x4 cv = {0.f, 0.f, 0.f, 0.f};
        cv = __builtin_amdgcn_mfma_f32_16x16x32_fp8_fp8(fp4_to_fp8x8(a0), fp4_to_fp8x8(b0), cv, 0, 0, 0);
        cv = __builtin_amdgcn_mfma_f32_16x16x32_fp8_fp8(fp4_to_fp8x8(a1), fp4_to_fp8x8(b1), cv, 0, 0, 0);
        if (has && p0 < npairs) local += softplus_fast(sign * cv[reg] * invS2);
    }

    __shared__ float red[256];
    red[threadIdx.x] = local;
    __syncthreads();
    for (int s = blockDim.x / 2; s > 0; s >>= 1) {
        if ((int)threadIdx.x < s) red[threadIdx.x] += red[threadIdx.x + s];
        __syncthreads();
    }
    if (threadIdx.x == 0) atomicAdd(accum, (double)red[0]);
}

__global__ void finalize_kernel(const double* __restrict__ acc, float* __restrict__ out, int ep) {
    if (threadIdx.x == 0 && blockIdx.x == 0)
        out[0] = (float)(acc[0] / (double)ep);
}

// ---------------- launch ----------------

extern "C" void kernel_launch(void* const* d_in, const int* in_sizes, int n_in,
                              void* d_out, int out_size, void* d_ws, size_t ws_size,
                              hipStream_t stream) {
    const float* features = (const float*)d_in[0];
    const float* W1 = (const float*)d_in[1];
    const float* b1 = (const float*)d_in[2];
    const float* W2 = (const float*)d_in[3];
    const float* b2 = (const float*)d_in[4];
    const int* src     = (const int*)d_in[5];
    const int* dst     = (const int*)d_in[6];
    const int* pos_src = (const int*)d_in[7];
    const int* pos_dst = (const int*)d_in[8];
    const int* neg_src = (const int*)d_in[9];
    const int* neg_dst = (const int*)d_in[10];

    const int N    = in_sizes[0] / D;
    const int E    = in_sizes[5];
    const int EP   = in_sizes[7];
    const int ENEG = in_sizes[9];
    const int NB   = (N + NPB - 1) >> NPB_SHIFT;   // 1563 for N=100000

    char* ws = (char*)d_ws;
    size_t off = 0;
    auto alloc = [&](size_t bytes) -> void* {
        void* p = ws + off;
        off += (bytes + 255) & ~(size_t)255;
        return p;
    };
    int*    rs     = (int*)alloc((size_t)(N + 64) * 4);
    int*    harr   = (int*)alloc((size_t)NB * NPART * 4);
    int*    soff   = (int*)alloc((size_t)NB * NPART * 4);
    int*    bsum   = (int*)alloc(1024 * 4);
    int*    packed = (int*)alloc((size_t)E * 4);
    int*    csr    = (int*)alloc((size_t)E * 4);
    __half* anorm  = (__half*)alloc((size_t)N * D * 2);
    unsigned char* feat8 = (unsigned char*)alloc((size_t)N * D);
    unsigned char* h8    = (unsigned char*)alloc((size_t)N * D);
    unsigned char* emb8  = (unsigned char*)alloc((size_t)N * D);
    unsigned int*  emb4  = (unsigned int*)alloc((size_t)N * D / 2);
    unsigned int*  amax  = (unsigned int*)alloc(AMAX_SLOTS * 16 * 4);
    double* acc    = (double*)alloc(8);

    hipMemsetAsync(acc, 0, 8, stream);
    hipMemsetAsync(amax, 0, AMAX_SLOTS * 16 * 4, stream);

    const int chunk = (E + NPART - 1) / NPART;     // 3125
    const size_t ldsNB = (size_t)NB * 4;
    const int n4 = (N * D) / 4;

    hist_f2f8_kernel<<<NPART + (n4 + 255) / 256, 256, ldsNB, stream>>>(
        dst, harr, E, NB, chunk, features, feat8, n4);
    const int scn = NB * NPART;                    // 800,256
    const int nbs = (scn + 1023) / 1024;           // 782 <= 1024
    scan1_kernel<<<nbs, 1024, 0, stream>>>(harr, soff, bsum, scn);
    scan2_kernel<<<1, 1024, 0, stream>>>(bsum, nbs);
    part_scatter_kernel<<<NPART, 256, ldsNB, stream>>>(src, dst, soff, bsum, packed, E, NB, chunk);
    bucket_build_kernel<<<NB, 256, 0, stream>>>(soff, bsum, packed, csr, rs, N, E, NB);

    const int ngroups = (N + NV - 1) / NV;        // 50,000
    const int ab = (ngroups * 8 + 255) / 256;     // 1563 blocks
    const int ntiles16 = (N + 15) / 16;           // 6250
    const int pb2 = (ntiles16 + 3) / 4;           // 1563 blocks

    // layer 1
    agg_kernel<<<ab, 256, 0, stream>>>(feat8, csr, rs, anorm, N, E);
    post_mfma_kernel<1, 0><<<pb2, 256, 0, stream>>>(anorm, h8, W1, b1, N, nullptr);

    // layer 2 (+ slot-spread absmax for fp4 scale)
    agg_kernel<<<ab, 256, 0, stream>>>(h8, csr, rs, anorm, N, E);
    post_mfma_kernel<0, 1><<<pb2, 256, 0, stream>>>(anorm, emb8, W2, b2, N, amax);

    // fp8 -> fp4 table (3.2 MB, fits per-XCD L2)
    const int ng8 = N * D / 8;                    // 800,000 groups
    quant4_kernel<<<(ng8 + 255) / 256, 256, 0, stream>>>(emb8, emb4, amax, ng8);

    int pbp = ((EP + 15) / 16 + 3) / 4;  if (pbp > 2048) pbp = 2048; if (pbp < 1) pbp = 1;
    int pbn = ((ENEG + 15) / 16 + 3) / 4; if (pbn > 2048) pbn = 2048;
    score_both_kernel<<<pbp + pbn, 256, 0, stream>>>(
        emb4, pos_src, pos_dst, neg_src, neg_dst, EP, ENEG, pbp, amax, acc);

    finalize_kernel<<<1, 64, 0, stream>>>(acc, (float*)d_out, EP);
}

// Round 21
// 216.909 us; speedup vs baseline: 1.3341x; 1.1281x over previous
//
#include <hip/hip_runtime.h>
#include <hip/hip_fp16.h>
#include <math.h>

#define D 64
#define NPB 64           // nodes per bucket
#define NPB_SHIFT 6
#define LCAP 2560        // LDS capacity per bucket (mean ~1024)
#define NPART 512        // edge partitions (2 blocks/CU)
#define NV 2             // nodes owned per 8-lane group in agg_kernel

typedef _Float16 half4v __attribute__((ext_vector_type(4)));
typedef float f32x4 __attribute__((ext_vector_type(4)));
typedef float f32x2v __attribute__((ext_vector_type(2)));

// ---------------- scan chain: scan1 + scan2; scan3 folded into consumers ----------------

__global__ void scan1_kernel(const int* __restrict__ in, int* __restrict__ out,
                             int* __restrict__ bsum, int n) {
    __shared__ int s[1024];
    int t = threadIdx.x;
    int i = blockIdx.x * 1024 + t;
    int v = (i < n) ? in[i] : 0;
    s[t] = v;
    __syncthreads();
    for (int off = 1; off < 1024; off <<= 1) {
        int add = (t >= off) ? s[t - off] : 0;
        __syncthreads();
        s[t] += add;
        __syncthreads();
    }
    if (i < n) out[i] = s[t] - v;
    if (t == 1023) bsum[blockIdx.x] = s[1023];
}

__global__ void scan2_kernel(int* __restrict__ bsum, int nb) {
    __shared__ int s[1024];
    int t = threadIdx.x;
    int v = (t < nb) ? bsum[t] : 0;
    s[t] = v;
    __syncthreads();
    for (int off = 1; off < 1024; off <<= 1) {
        int add = (t >= off) ? s[t - off] : 0;
        __syncthreads();
        s[t] += add;
        __syncthreads();
    }
    if (t < nb) bsum[t] = s[t] - v;
}

// ---------------- hist (blocks < NPART) + f2f8 (blocks >= NPART), one dispatch ----------------

__global__ __launch_bounds__(256) void hist_f2f8_kernel(
    const int* __restrict__ dst, int* __restrict__ harr,
    int e, int nb, int chunk,
    const float* __restrict__ fin, unsigned char* __restrict__ f8out, int n4)
{
    extern __shared__ int sh[];
    if ((int)blockIdx.x < NPART) {
        const int p = blockIdx.x;
        for (int i = threadIdx.x; i < nb; i += 256) sh[i] = 0;
        __syncthreads();
        const int s = p * chunk, ee = min(e, s + chunk);
        for (int i = s + threadIdx.x; i < ee; i += 256)
            atomicAdd(&sh[dst[i] >> NPB_SHIFT], 1);
        __syncthreads();
        for (int b = threadIdx.x; b < nb; b += 256) harr[b * NPART + p] = sh[b];
    } else {
        int i = (blockIdx.x - NPART) * 256 + threadIdx.x;
        if (i < n4) {
            float4 v = *(const float4*)(fin + (size_t)i * 4);
            int pk0 = __builtin_amdgcn_cvt_pk_fp8_f32(v.x, v.y, 0, false);
            int pk1 = __builtin_amdgcn_cvt_pk_fp8_f32(v.z, v.w, 0, false);
            ((unsigned int*)f8out)[i] = (unsigned int)(pk0 & 0xFFFF) | ((unsigned int)(pk1 & 0xFFFF) << 16);
        }
    }
}

// soff_full(i) = soff[i] + bsum[i>>10]  (scan3 folded)
__global__ __launch_bounds__(256) void part_scatter_kernel(
    const int* __restrict__ src, const int* __restrict__ dst,
    const int* __restrict__ soff, const int* __restrict__ bsum,
    int* __restrict__ packed, int e, int nb, int chunk)
{
    extern __shared__ int cur[];
    const int p = blockIdx.x;
    for (int b = threadIdx.x; b < nb; b += 256) {
        int idx = b * NPART + p;
        cur[b] = soff[idx] + bsum[idx >> 10];
    }
    __syncthreads();
    const int s = p * chunk, ee = min(e, s + chunk);
    for (int i = s + threadIdx.x; i < ee; i += 256) {
        int d = dst[i];
        int pos = atomicAdd(&cur[d >> NPB_SHIFT], 1);
        packed[pos] = src[i] | ((d & (NPB - 1)) << 24);
    }
}

// per-bucket: dst-sort packed in LDS, emit csr (src only) + rs
__global__ __launch_bounds__(256) void bucket_build_kernel(
    const int* __restrict__ soff, const int* __restrict__ bsum,
    const int* __restrict__ packed,
    int* __restrict__ csr, int* __restrict__ rs,
    int n, int e_total, int nb)
{
    __shared__ int lcsr[LCAP];
    __shared__ int dcount[NPB];
    __shared__ int dexcl[NPB];
    __shared__ int cur2[NPB];
    const int b    = blockIdx.x;
    const int i0x  = b * NPART;
    const int base = soff[i0x] + bsum[i0x >> 10];
    int end;
    if (b + 1 < nb) {
        const int i1x = (b + 1) * NPART;
        end = soff[i1x] + bsum[i1x >> 10];
    } else {
        end = e_total;
    }
    const int cnt  = end - base;
    const int nb0  = b << NPB_SHIFT;
    const int nnode = min(NPB, n - nb0);
    const int tid  = threadIdx.x;

    if (tid < NPB) { dcount[tid] = 0; cur2[tid] = 0; }
    __syncthreads();

    for (int i = tid; i < cnt; i += 256)
        atomicAdd(&dcount[(packed[base + i] >> 24) & (NPB - 1)], 1);
    __syncthreads();
    if (tid == 0) {
        int run = 0;
        for (int t = 0; t < nnode; ++t) { dexcl[t] = run; run += dcount[t]; }
    }
    __syncthreads();
    if (tid < nnode) rs[nb0 + tid] = base + dexcl[tid];

    if (cnt <= LCAP) {
        for (int i = tid; i < cnt; i += 256) {
            int pk = packed[base + i];
            int ln = (pk >> 24) & (NPB - 1);
            int pos = dexcl[ln] + atomicAdd(&cur2[ln], 1);
            lcsr[pos] = pk & 0xFFFFFF;
        }
        __syncthreads();
        for (int i = tid; i < cnt; i += 256) csr[base + i] = lcsr[i];
    } else {
        for (int i = tid; i < cnt; i += 256) {
            int pk = packed[base + i];
            int ln = (pk >> 24) & (NPB - 1);
            int pos = dexcl[ln] + atomicAdd(&cur2[ln], 1);
            csr[base + pos] = pk & 0xFFFFFF;
        }
    }
}

// ---------------- fp8 -> f32 unpack helper ----------------

__device__ __forceinline__ void cvt8(int2 w, float* x) {
    f32x2v a0 = __builtin_amdgcn_cvt_pk_f32_fp8(w.x, false);
    f32x2v a1 = __builtin_amdgcn_cvt_pk_f32_fp8(w.x, true);
    f32x2v a2 = __builtin_amdgcn_cvt_pk_f32_fp8(w.y, false);
    f32x2v a3 = __builtin_amdgcn_cvt_pk_f32_fp8(w.y, true);
    x[0] = a0[0]; x[1] = a0[1]; x[2] = a1[0]; x[3] = a1[1];
    x[4] = a2[0]; x[5] = a2[1]; x[6] = a3[0]; x[7] = a3[1];
}

// ---------------- aggregation: node-owned fp8 gather, prefetch-4 ----------------

__global__ __launch_bounds__(256) void agg_kernel(
    const unsigned char* __restrict__ in8, const int* __restrict__ csr,
    const int* __restrict__ rs, __half* __restrict__ anorm,
    int n, int e_total)
{
    const int ll = threadIdx.x & 7;
    const int g  = (blockIdx.x * 256 + threadIdx.x) >> 3;
    const int v0 = g * NV;
    if (v0 >= n) return;

    #pragma unroll
    for (int t = 0; t < NV; ++t) {
        const int v = v0 + t;
        if (v >= n) break;
        const int i0 = rs[v];
        const int i1 = (v + 1 < n) ? rs[v + 1] : e_total;
        const int m  = i1 - i0;

        float acc[8];
        #pragma unroll
        for (int j = 0; j < 8; ++j) acc[j] = 0.0f;

        int2 f0, f1, f2, f3;
        if (m > 0) f0 = *(const int2*)(in8 + ((size_t)csr[i0] << 6) + (ll << 3));
        if (m > 1) f1 = *(const int2*)(in8 + ((size_t)csr[i0 + 1] << 6) + (ll << 3));
        if (m > 2) f2 = *(const int2*)(in8 + ((size_t)csr[i0 + 2] << 6) + (ll << 3));
        if (m > 3) f3 = *(const int2*)(in8 + ((size_t)csr[i0 + 3] << 6) + (ll << 3));
        for (int i = 0; i < m; ++i) {
            int2 fn;
            if (i + 4 < m) fn = *(const int2*)(in8 + ((size_t)csr[i0 + i + 4] << 6) + (ll << 3));
            float x[8]; cvt8(f0, x);
            #pragma unroll
            for (int j = 0; j < 8; ++j) acc[j] += x[j];
            f0 = f1; f1 = f2; f2 = f3; f3 = fn;
        }

        int2 sf = *(const int2*)(in8 + ((size_t)v << 6) + (ll << 3));
        float sx[8]; cvt8(sf, sx);
        const float inv = 1.0f / (float)(m + 1);
        union { __half h[8]; float4 f; } u;
        #pragma unroll
        for (int j = 0; j < 8; ++j) u.h[j] = __float2half((acc[j] + sx[j]) * inv);
        *(float4*)(anorm + (size_t)v * D + ll * 8) = u.f;
    }
}

// ---------------- post: [16 x 64] @ [64 x 64] via v_mfma_f32_16x16x16f16 ----------------

template<int RELU>
__global__ __launch_bounds__(256) void post_mfma_kernel(
    const __half* __restrict__ anorm, unsigned char* __restrict__ out8,
    const float* __restrict__ W, const float* __restrict__ bias, int n)
{
    const int lane = threadIdx.x & 63;
    const int w    = threadIdx.x >> 6;
    const int tile = blockIdx.x * 4 + w;
    const int v0   = tile * 16;
    if (v0 >= n) return;

    const int col = lane & 15;
    const int kb  = (lane >> 4) * 4;

    half4v bf[4][4];
    #pragma unroll
    for (int kt = 0; kt < 4; ++kt)
        #pragma unroll
        for (int t = 0; t < 4; ++t)
            #pragma unroll
            for (int j = 0; j < 4; ++j)
                bf[kt][t][j] = (_Float16)W[(kt * 16 + kb + j) * D + t * 16 + col];

    int vr = v0 + col; if (vr >= n) vr = n - 1;
    const __half* ap = anorm + (size_t)vr * D + kb;
    half4v af[4];
    #pragma unroll
    for (int kt = 0; kt < 4; ++kt)
        af[kt] = *(const half4v*)(ap + kt * 16);

    f32x4 c[4];
    #pragma unroll
    for (int t = 0; t < 4; ++t) {
        float bv = bias[t * 16 + col];
        c[t] = (f32x4){bv, bv, bv, bv};
    }
    #pragma unroll
    for (int kt = 0; kt < 4; ++kt)
        #pragma unroll
        for (int t = 0; t < 4; ++t)
            c[t] = __builtin_amdgcn_mfma_f32_16x16x16f16(af[kt], bf[kt][t], c[t], 0, 0, 0);

    #pragma unroll
    for (int t = 0; t < 4; ++t)
        #pragma unroll
        for (int p = 0; p < 4; ++p) {
            int r = v0 + (lane >> 4) * 4 + p;
            if (r < n) {
                float o = c[t][p];
                if (RELU) o = fmaxf(o, 0.0f);
                int pk = __builtin_amdgcn_cvt_pk_fp8_f32(o, o, 0, false);
                out8[(size_t)r * D + t * 16 + col] = (unsigned char)(pk & 0xFF);
            }
        }
}

// ---------------- Scoring: pos+neg in one dispatch; diag of Ea@Eb^T via fp8 MFMA ----------------

__device__ __forceinline__ float softplus_fast(float x) {
    return fmaxf(x, 0.0f) + __logf(1.0f + __expf(-fabsf(x)));
}

__global__ __launch_bounds__(256) void score_both_kernel(
    const unsigned char* __restrict__ emb8,
    const int* __restrict__ pos_src, const int* __restrict__ pos_dst,
    const int* __restrict__ neg_src, const int* __restrict__ neg_dst,
    int ep, int eneg, int pblocks, double* __restrict__ accum)
{
    const int* a_idx; const int* b_idx;
    int npairs, bid, nblk;
    float sign;
    if ((int)blockIdx.x < pblocks) {
        a_idx = pos_src; b_idx = pos_dst; npairs = ep; sign = -1.0f;
        bid = blockIdx.x; nblk = pblocks;
    } else {
        a_idx = neg_src; b_idx = neg_dst; npairs = eneg; sign = 1.0f;
        bid = blockIdx.x - pblocks; nblk = gridDim.x - pblocks;
    }

    const int lane = threadIdx.x & 63;
    const int gw   = (bid * 256 + (int)threadIdx.x) >> 6;
    const int nw   = (nblk * 256) >> 6;
    const int ntiles = (npairs + 15) >> 4;
    const int ftiles = npairs >> 4;

    const int pr = lane & 15;
    const int ks = lane >> 4;
    const bool has = (ks == (pr >> 2));
    const int reg  = pr & 3;

    float local = 0.0f;

    int t = gw;
    for (; t + 3 * nw < ftiles; t += 4 * nw) {
        int ti[4] = {t, t + nw, t + 2 * nw, t + 3 * nw};
        long av[4][2], bv[4][2];
        #pragma unroll
        for (int u = 0; u < 4; ++u) {
            int p0 = ti[u] * 16 + pr;
            int ia = a_idx[p0], ib = b_idx[p0];
            const unsigned char* pa = emb8 + ((size_t)ia << 6) + ks * 8;
            const unsigned char* pb = emb8 + ((size_t)ib << 6) + ks * 8;
            av[u][0] = *(const long*)pa;
            av[u][1] = *(const long*)(pa + 32);
            bv[u][0] = *(const long*)pb;
            bv[u][1] = *(const long*)(pb + 32);
        }
        #pragma unroll
        for (int u = 0; u < 4; ++u) {
            f32x4 cv = {0.f, 0.f, 0.f, 0.f};
            cv = __builtin_amdgcn_mfma_f32_16x16x32_fp8_fp8(av[u][0], bv[u][0], cv, 0, 0, 0);
            cv = __builtin_amdgcn_mfma_f32_16x16x32_fp8_fp8(av[u][1], bv[u][1], cv, 0, 0, 0);
            if (has) local += softplus_fast(sign * cv[reg]);
        }
    }
    for (; t < ntiles; t += nw) {
        int p0 = t * 16 + pr;
        int c0 = min(p0, npairs - 1);
        int ia = a_idx[c0], ib = b_idx[c0];
        const unsigned char* pa = emb8 + ((size_t)ia << 6) + ks * 8;
        const unsigned char* pb = emb8 + ((size_t)ib << 6) + ks * 8;
        long a0 = *(const long*)pa;
        long a1 = *(const long*)(pa + 32);
        long b0 = *(const long*)pb;
        long b1 = *(const long*)(pb + 32);
        f32x4 cv = {0.f, 0.f, 0.f, 0.f};
        cv = __builtin_amdgcn_mfma_f32_16x16x32_fp8_fp8(a0, b0, cv, 0, 0, 0);
        cv = __builtin_amdgcn_mfma_f32_16x16x32_fp8_fp8(a1, b1, cv, 0, 0, 0);
        if (has && p0 < npairs) local += softplus_fast(sign * cv[reg]);
    }

    __shared__ float red[256];
    red[threadIdx.x] = local;
    __syncthreads();
    for (int s = blockDim.x / 2; s > 0; s >>= 1) {
        if ((int)threadIdx.x < s) red[threadIdx.x] += red[threadIdx.x + s];
        __syncthreads();
    }
    if (threadIdx.x == 0) atomicAdd(accum, (double)red[0]);
}

__global__ void finalize_kernel(const double* __restrict__ acc, float* __restrict__ out, int ep) {
    if (threadIdx.x == 0 && blockIdx.x == 0)
        out[0] = (float)(acc[0] / (double)ep);
}

// ---------------- launch ----------------

extern "C" void kernel_launch(void* const* d_in, const int* in_sizes, int n_in,
                              void* d_out, int out_size, void* d_ws, size_t ws_size,
                              hipStream_t stream) {
    const float* features = (const float*)d_in[0];
    const float* W1 = (const float*)d_in[1];
    const float* b1 = (const float*)d_in[2];
    const float* W2 = (const float*)d_in[3];
    const float* b2 = (const float*)d_in[4];
    const int* src     = (const int*)d_in[5];
    const int* dst     = (const int*)d_in[6];
    const int* pos_src = (const int*)d_in[7];
    const int* pos_dst = (const int*)d_in[8];
    const int* neg_src = (const int*)d_in[9];
    const int* neg_dst = (const int*)d_in[10];

    const int N    = in_sizes[0] / D;
    const int E    = in_sizes[5];
    const int EP   = in_sizes[7];
    const int ENEG = in_sizes[9];
    const int NB   = (N + NPB - 1) >> NPB_SHIFT;   // 1563 for N=100000

    char* ws = (char*)d_ws;
    size_t off = 0;
    auto alloc = [&](size_t bytes) -> void* {
        void* p = ws + off;
        off += (bytes + 255) & ~(size_t)255;
        return p;
    };
    int*    rs     = (int*)alloc((size_t)(N + 64) * 4);
    int*    harr   = (int*)alloc((size_t)NB * NPART * 4);
    int*    soff   = (int*)alloc((size_t)NB * NPART * 4);
    int*    bsum   = (int*)alloc(1024 * 4);
    int*    packed = (int*)alloc((size_t)E * 4);
    int*    csr    = (int*)alloc((size_t)E * 4);
    __half* anorm  = (__half*)alloc((size_t)N * D * 2);
    unsigned char* feat8 = (unsigned char*)alloc((size_t)N * D);
    unsigned char* h8    = (unsigned char*)alloc((size_t)N * D);
    unsigned char* emb8  = (unsigned char*)alloc((size_t)N * D);
    double* acc    = (double*)alloc(8);

    hipMemsetAsync(acc, 0, 8, stream);

    const int chunk = (E + NPART - 1) / NPART;     // 3125
    const size_t ldsNB = (size_t)NB * 4;
    const int n4 = (N * D) / 4;

    hist_f2f8_kernel<<<NPART + (n4 + 255) / 256, 256, ldsNB, stream>>>(
        dst, harr, E, NB, chunk, features, feat8, n4);
    const int scn = NB * NPART;                    // 800,256
    const int nbs = (scn + 1023) / 1024;           // 782 <= 1024
    scan1_kernel<<<nbs, 1024, 0, stream>>>(harr, soff, bsum, scn);
    scan2_kernel<<<1, 1024, 0, stream>>>(bsum, nbs);
    part_scatter_kernel<<<NPART, 256, ldsNB, stream>>>(src, dst, soff, bsum, packed, E, NB, chunk);
    bucket_build_kernel<<<NB, 256, 0, stream>>>(soff, bsum, packed, csr, rs, N, E, NB);

    const int ngroups = (N + NV - 1) / NV;        // 50,000
    const int ab = (ngroups * 8 + 255) / 256;     // 1563 blocks
    const int ntiles16 = (N + 15) / 16;           // 6250
    const int pb2 = (ntiles16 + 3) / 4;           // 1563 blocks

    // layer 1
    agg_kernel<<<ab, 256, 0, stream>>>(feat8, csr, rs, anorm, N, E);
    post_mfma_kernel<1><<<pb2, 256, 0, stream>>>(anorm, h8, W1, b1, N);

    // layer 2
    agg_kernel<<<ab, 256, 0, stream>>>(h8, csr, rs, anorm, N, E);
    post_mfma_kernel<0><<<pb2, 256, 0, stream>>>(anorm, emb8, W2, b2, N);

    int pbp = ((EP + 15) / 16 + 3) / 4;  if (pbp > 2048) pbp = 2048; if (pbp < 1) pbp = 1;
    int pbn = ((ENEG + 15) / 16 + 3) / 4; if (pbn > 2048) pbn = 2048;
    score_both_kernel<<<pbp + pbn, 256, 0, stream>>>(
        emb8, pos_src, pos_dst, neg_src, neg_dst, EP, ENEG, pbp, acc);

    finalize_kernel<<<1, 64, 0, stream>>>(acc, (float*)d_out, EP);
}